// Round 1
// baseline (814.376 us; speedup 1.0000x reference)
//
#include <hip/hip_runtime.h>

#define TTOK   8192
#define BGR    32
#define NNODE  256
#define DIM    128
#define NH     8
#define HD     16
#define NEDGE  262144
#define SCALE_QK 0.25f

// ---------------- GEMM ----------------
struct GemmJob {
  const float*  A1;
  const float*  A2;
  const float2* ss1;
  const float2* ss2;
  const float*  W;
  const float*  bias;
  const float*  res;
  float*        C;
};

// AMODE: 0 = A1 (lda=K); 1 = A1+A2 (both [M,128]); 2 = concat(bn(A1,ss1), bn(A2,ss2)) K=256
template<int AMODE, int RELU, int HASRES>
__global__ __launch_bounds__(256) void gemm_k(GemmJob j0, GemmJob j1, GemmJob j2,
                                              int M, int N, int K)
{
  const GemmJob jb = (blockIdx.z == 0) ? j0 : ((blockIdx.z == 1) ? j1 : j2);
  __shared__ float As[32][68];   // [k][m], transposed
  __shared__ float Ws[32][68];   // [k][n]
  const int bm = blockIdx.y * 64;
  const int bn = blockIdx.x * 64;
  const int tid = threadIdx.x;
  const int tx = tid & 15, ty = tid >> 4;
  const int r0 = ty * 4, c0 = tx * 4;
  float acc00=0,acc01=0,acc02=0,acc03=0;
  float acc10=0,acc11=0,acc12=0,acc13=0;
  float acc20=0,acc21=0,acc22=0,acc23=0;
  float acc30=0,acc31=0,acc32=0,acc33=0;

  for (int bk = 0; bk < K; bk += 32) {
    // A tile 64x32 -> As (transposed)
    {
      const int rbase = tid >> 3;
      const int kg = (tid & 7) * 4;
      #pragma unroll
      for (int half = 0; half < 2; half++) {
        const int rr = rbase + half * 32;
        const int row = bm + rr;
        const int k0 = bk + kg;
        float4 a;
        if (AMODE == 0) {
          a = *(const float4*)(jb.A1 + (size_t)row * K + k0);
        } else if (AMODE == 1) {
          float4 u = *(const float4*)(jb.A1 + (size_t)row * 128 + k0);
          float4 w = *(const float4*)(jb.A2 + (size_t)row * 128 + k0);
          a = make_float4(u.x + w.x, u.y + w.y, u.z + w.z, u.w + w.w);
        } else {
          if (k0 < 128) {
            float4 u = *(const float4*)(jb.A1 + (size_t)row * 128 + k0);
            float2 s0 = jb.ss1[k0], s1 = jb.ss1[k0+1], s2 = jb.ss1[k0+2], s3 = jb.ss1[k0+3];
            a = make_float4(u.x*s0.x+s0.y, u.y*s1.x+s1.y, u.z*s2.x+s2.y, u.w*s3.x+s3.y);
          } else {
            const int kq = k0 - 128;
            float4 u = *(const float4*)(jb.A2 + (size_t)row * 128 + kq);
            float2 s0 = jb.ss2[kq], s1 = jb.ss2[kq+1], s2 = jb.ss2[kq+2], s3 = jb.ss2[kq+3];
            a = make_float4(u.x*s0.x+s0.y, u.y*s1.x+s1.y, u.z*s2.x+s2.y, u.w*s3.x+s3.y);
          }
        }
        As[kg+0][rr] = a.x; As[kg+1][rr] = a.y; As[kg+2][rr] = a.z; As[kg+3][rr] = a.w;
      }
    }
    // W tile 32x64
    {
      const int kb = tid >> 4;
      const int cg = (tid & 15) * 4;
      #pragma unroll
      for (int half = 0; half < 2; half++) {
        const int kk2 = kb + half * 16;
        float4 w = *(const float4*)(jb.W + (size_t)(bk + kk2) * N + bn + cg);
        *(float4*)&Ws[kk2][cg] = w;
      }
    }
    __syncthreads();
    #pragma unroll
    for (int kk = 0; kk < 32; kk++) {
      const float4 av = *(const float4*)&As[kk][r0];
      const float4 bv = *(const float4*)&Ws[kk][c0];
      const float a0 = av.x, a1 = av.y, a2 = av.z, a3 = av.w;
      const float b0 = bv.x, b1 = bv.y, b2 = bv.z, b3 = bv.w;
      acc00 = fmaf(a0,b0,acc00); acc01 = fmaf(a0,b1,acc01); acc02 = fmaf(a0,b2,acc02); acc03 = fmaf(a0,b3,acc03);
      acc10 = fmaf(a1,b0,acc10); acc11 = fmaf(a1,b1,acc11); acc12 = fmaf(a1,b2,acc12); acc13 = fmaf(a1,b3,acc13);
      acc20 = fmaf(a2,b0,acc20); acc21 = fmaf(a2,b1,acc21); acc22 = fmaf(a2,b2,acc22); acc23 = fmaf(a2,b3,acc23);
      acc30 = fmaf(a3,b0,acc30); acc31 = fmaf(a3,b1,acc31); acc32 = fmaf(a3,b2,acc32); acc33 = fmaf(a3,b3,acc33);
    }
    __syncthreads();
  }

  const float bb0 = jb.bias[bn+c0+0], bb1 = jb.bias[bn+c0+1], bb2 = jb.bias[bn+c0+2], bb3 = jb.bias[bn+c0+3];
  #pragma unroll
  for (int i = 0; i < 4; i++) {
    const int row = bm + r0 + i;
    float o0, o1, o2, o3;
    if (i == 0) { o0=acc00; o1=acc01; o2=acc02; o3=acc03; }
    else if (i == 1) { o0=acc10; o1=acc11; o2=acc12; o3=acc13; }
    else if (i == 2) { o0=acc20; o1=acc21; o2=acc22; o3=acc23; }
    else { o0=acc30; o1=acc31; o2=acc32; o3=acc33; }
    o0 += bb0; o1 += bb1; o2 += bb2; o3 += bb3;
    if (RELU) { o0 = fmaxf(o0,0.f); o1 = fmaxf(o1,0.f); o2 = fmaxf(o2,0.f); o3 = fmaxf(o3,0.f); }
    if (HASRES) {
      float4 r = *(const float4*)(jb.res + (size_t)row * N + bn + c0);
      o0 += r.x; o1 += r.y; o2 += r.z; o3 += r.w;
    }
    *(float4*)(jb.C + (size_t)row * N + bn + c0) = make_float4(o0,o1,o2,o3);
  }
}

// ---------------- Fused attention (per (b,h) block) ----------------
__global__ __launch_bounds__(256) void attn_k(
    const float* __restrict__ q, const float* __restrict__ k, const float* __restrict__ v,
    const float* __restrict__ tptr, float* __restrict__ fc, float* __restrict__ ff,
    float* __restrict__ dout)
{
  const int bh = blockIdx.x;
  const int b = bh >> 3, h = bh & 7;
  __shared__ float kT[16][260];
  __shared__ float vT[16][260];
  __shared__ float entw[4][2];
  const int tid = threadIdx.x;
  {
    const int j = tid;
    const float* kr = k + ((size_t)(b*NNODE + j))*DIM + h*HD;
    const float* vr = v + ((size_t)(b*NNODE + j))*DIM + h*HD;
    #pragma unroll
    for (int p = 0; p < 4; p++) {
      float4 kv = *(const float4*)(kr + 4*p);
      kT[4*p+0][j] = kv.x; kT[4*p+1][j] = kv.y; kT[4*p+2][j] = kv.z; kT[4*p+3][j] = kv.w;
      float4 vv = *(const float4*)(vr + 4*p);
      vT[4*p+0][j] = vv.x; vT[4*p+1][j] = vv.y; vT[4*p+2][j] = vv.z; vT[4*p+3][j] = vv.w;
    }
  }
  __syncthreads();
  const float sc = SCALE_QK / tptr[0];
  const int wv = tid >> 6, lane = tid & 63;
  float entc = 0.f, entf = 0.f;

  for (int i0 = wv*2; i0 < NNODE; i0 += 8) {
    const float* q0r = q + ((size_t)(b*NNODE + i0))*DIM + h*HD;
    float qa[16], qb[16];
    #pragma unroll
    for (int p = 0; p < 4; p++) {
      float4 a = *(const float4*)(q0r + 4*p);
      qa[4*p+0]=a.x; qa[4*p+1]=a.y; qa[4*p+2]=a.z; qa[4*p+3]=a.w;
      float4 c = *(const float4*)(q0r + DIM + 4*p);
      qb[4*p+0]=c.x; qb[4*p+1]=c.y; qb[4*p+2]=c.z; qb[4*p+3]=c.w;
    }
    float s0[4] = {0,0,0,0}, s1[4] = {0,0,0,0};
    #pragma unroll
    for (int d = 0; d < 16; d++) {
      const float4 kv = *(const float4*)&kT[d][lane*4];
      s0[0] = fmaf(qa[d], kv.x, s0[0]); s0[1] = fmaf(qa[d], kv.y, s0[1]);
      s0[2] = fmaf(qa[d], kv.z, s0[2]); s0[3] = fmaf(qa[d], kv.w, s0[3]);
      s1[0] = fmaf(qb[d], kv.x, s1[0]); s1[1] = fmaf(qb[d], kv.y, s1[1]);
      s1[2] = fmaf(qb[d], kv.z, s1[2]); s1[3] = fmaf(qb[d], kv.w, s1[3]);
    }
    #pragma unroll
    for (int m = 0; m < 4; m++) { s0[m] *= sc; s1[m] *= sc; }

    float mx0 = fmaxf(fmaxf(s0[0],s0[1]),fmaxf(s0[2],s0[3]));
    float mn0 = fminf(fminf(s0[0],s0[1]),fminf(s0[2],s0[3]));
    float mx1 = fmaxf(fmaxf(s1[0],s1[1]),fmaxf(s1[2],s1[3]));
    float mn1 = fminf(fminf(s1[0],s1[1]),fminf(s1[2],s1[3]));
    #pragma unroll
    for (int off = 1; off < 64; off <<= 1) {
      mx0 = fmaxf(mx0, __shfl_xor(mx0, off)); mn0 = fminf(mn0, __shfl_xor(mn0, off));
      mx1 = fmaxf(mx1, __shfl_xor(mx1, off)); mn1 = fminf(mn1, __shfl_xor(mn1, off));
    }
    float ec0[4], ef0[4], ec1[4], ef1[4];
    float zc0=0,zf0=0,zc1=0,zf1=0;
    #pragma unroll
    for (int m = 0; m < 4; m++) {
      ec0[m] = __expf(s0[m]-mx0); zc0 += ec0[m];
      ef0[m] = __expf(mn0-s0[m]); zf0 += ef0[m];
      ec1[m] = __expf(s1[m]-mx1); zc1 += ec1[m];
      ef1[m] = __expf(mn1-s1[m]); zf1 += ef1[m];
    }
    #pragma unroll
    for (int off = 1; off < 64; off <<= 1) {
      zc0 += __shfl_xor(zc0, off); zf0 += __shfl_xor(zf0, off);
      zc1 += __shfl_xor(zc1, off); zf1 += __shfl_xor(zf1, off);
    }
    const float rc0 = 1.f/zc0, rf0 = 1.f/zf0, rc1 = 1.f/zc1, rf1 = 1.f/zf1;
    #pragma unroll
    for (int m = 0; m < 4; m++) {
      float p;
      p = fminf(fmaxf(ec0[m]*rc0, 1e-10f), 1.f-1e-10f); entc -= p*__logf(p);
      p = fminf(fmaxf(ef0[m]*rf0, 1e-10f), 1.f-1e-10f); entf -= p*__logf(p);
      p = fminf(fmaxf(ec1[m]*rc1, 1e-10f), 1.f-1e-10f); entc -= p*__logf(p);
      p = fminf(fmaxf(ef1[m]*rf1, 1e-10f), 1.f-1e-10f); entf -= p*__logf(p);
    }
    float o0c[16], o0f[16], o1c[16], o1f[16];
    #pragma unroll
    for (int d = 0; d < 16; d++) {
      const float4 vv = *(const float4*)&vT[d][lane*4];
      o0c[d] = ec0[0]*vv.x + ec0[1]*vv.y + ec0[2]*vv.z + ec0[3]*vv.w;
      o0f[d] = ef0[0]*vv.x + ef0[1]*vv.y + ef0[2]*vv.z + ef0[3]*vv.w;
      o1c[d] = ec1[0]*vv.x + ec1[1]*vv.y + ec1[2]*vv.z + ec1[3]*vv.w;
      o1f[d] = ef1[0]*vv.x + ef1[1]*vv.y + ef1[2]*vv.z + ef1[3]*vv.w;
    }
    #pragma unroll
    for (int off = 1; off < 64; off <<= 1) {
      #pragma unroll
      for (int d = 0; d < 16; d++) {
        o0c[d] += __shfl_xor(o0c[d], off);
        o0f[d] += __shfl_xor(o0f[d], off);
        o1c[d] += __shfl_xor(o1c[d], off);
        o1f[d] += __shfl_xor(o1f[d], off);
      }
    }
    if (lane == 0) {
      float* p0c = fc + ((size_t)(b*NNODE + i0))*DIM + h*HD;
      float* p0f = ff + ((size_t)(b*NNODE + i0))*DIM + h*HD;
      float* p1c = p0c + DIM;
      float* p1f = p0f + DIM;
      *(float4*)(p0c+0)  = make_float4(o0c[0]*rc0,  o0c[1]*rc0,  o0c[2]*rc0,  o0c[3]*rc0);
      *(float4*)(p0c+4)  = make_float4(o0c[4]*rc0,  o0c[5]*rc0,  o0c[6]*rc0,  o0c[7]*rc0);
      *(float4*)(p0c+8)  = make_float4(o0c[8]*rc0,  o0c[9]*rc0,  o0c[10]*rc0, o0c[11]*rc0);
      *(float4*)(p0c+12) = make_float4(o0c[12]*rc0, o0c[13]*rc0, o0c[14]*rc0, o0c[15]*rc0);
      *(float4*)(p0f+0)  = make_float4(o0f[0]*rf0,  o0f[1]*rf0,  o0f[2]*rf0,  o0f[3]*rf0);
      *(float4*)(p0f+4)  = make_float4(o0f[4]*rf0,  o0f[5]*rf0,  o0f[6]*rf0,  o0f[7]*rf0);
      *(float4*)(p0f+8)  = make_float4(o0f[8]*rf0,  o0f[9]*rf0,  o0f[10]*rf0, o0f[11]*rf0);
      *(float4*)(p0f+12) = make_float4(o0f[12]*rf0, o0f[13]*rf0, o0f[14]*rf0, o0f[15]*rf0);
      *(float4*)(p1c+0)  = make_float4(o1c[0]*rc1,  o1c[1]*rc1,  o1c[2]*rc1,  o1c[3]*rc1);
      *(float4*)(p1c+4)  = make_float4(o1c[4]*rc1,  o1c[5]*rc1,  o1c[6]*rc1,  o1c[7]*rc1);
      *(float4*)(p1c+8)  = make_float4(o1c[8]*rc1,  o1c[9]*rc1,  o1c[10]*rc1, o1c[11]*rc1);
      *(float4*)(p1c+12) = make_float4(o1c[12]*rc1, o1c[13]*rc1, o1c[14]*rc1, o1c[15]*rc1);
      *(float4*)(p1f+0)  = make_float4(o1f[0]*rf1,  o1f[1]*rf1,  o1f[2]*rf1,  o1f[3]*rf1);
      *(float4*)(p1f+4)  = make_float4(o1f[4]*rf1,  o1f[5]*rf1,  o1f[6]*rf1,  o1f[7]*rf1);
      *(float4*)(p1f+8)  = make_float4(o1f[8]*rf1,  o1f[9]*rf1,  o1f[10]*rf1, o1f[11]*rf1);
      *(float4*)(p1f+12) = make_float4(o1f[12]*rf1, o1f[13]*rf1, o1f[14]*rf1, o1f[15]*rf1);
    }
  }
  #pragma unroll
  for (int off = 1; off < 64; off <<= 1) {
    entc += __shfl_xor(entc, off);
    entf += __shfl_xor(entf, off);
  }
  if (lane == 0) { entw[wv][0] = entc; entw[wv][1] = entf; }
  __syncthreads();
  if (tid == 0) {
    const float tc = entw[0][0]+entw[1][0]+entw[2][0]+entw[3][0];
    const float tf = entw[0][1]+entw[1][1]+entw[2][1]+entw[3][1];
    dout[3145728 + bh] = tc * (1.0f/256.0f);
    dout[3145984 + bh] = tf * (1.0f/256.0f);
  }
}

// ---------------- Edge sigmoid mask (one thread per (edge, head)) ----------------
__global__ __launch_bounds__(256) void edge_k(
    const float* __restrict__ q, const float* __restrict__ k,
    const int* __restrict__ ei, float* __restrict__ maskout, float* __restrict__ emc)
{
  const int gt = blockIdx.x * 256 + threadIdx.x;   // 0 .. E*8-1
  const int e = gt >> 3, h = gt & 7;
  const int src = ei[e];
  const int dst = ei[NEDGE + e];
  const float* qr = q + (size_t)src * DIM + h*HD;
  const float* kr = k + (size_t)dst * DIM + h*HD;
  float s = 0.f;
  #pragma unroll
  for (int p = 0; p < 4; p++) {
    float4 a = *(const float4*)(qr + 4*p);
    float4 c = *(const float4*)(kr + 4*p);
    s += a.x*c.x + a.y*c.y + a.z*c.z + a.w*c.w;
  }
  s *= SCALE_QK;
  const float sig = 1.f / (1.f + __expf(-s));
  maskout[gt] = sig;
  float m = sig;
  m += __shfl_xor(m, 1); m += __shfl_xor(m, 2); m += __shfl_xor(m, 4);
  if ((threadIdx.x & 7) == 0) emc[e] = m * 0.125f;
}

// ---------------- GINE scatter-aggregate ----------------
__global__ __launch_bounds__(256) void gine_aggr_k(
    const float* __restrict__ x, const float* __restrict__ ea,
    const int* __restrict__ ei, const float* __restrict__ emc,
    float* __restrict__ aggrC, float* __restrict__ aggrF)
{
  __shared__ float accC[NNODE][32];
  __shared__ float accF[NNODE][32];
  const int cc = blockIdx.x;     // 0..3 column chunk
  const int b  = blockIdx.y;     // graph
  const int half = blockIdx.z;   // 0..1 edge half
  const int tid = threadIdx.x;
  const int c0 = cc * 32;
  for (int i = tid; i < NNODE*32; i += 256) { (&accC[0][0])[i] = 0.f; (&accF[0][0])[i] = 0.f; }
  __syncthreads();

  for (int t = tid; t < 4096; t += 256) {
    const int e = b*8192 + half*4096 + t;
    const int src = ei[e];
    const int dst = ei[NEDGE + e];
    const int ld = dst & 255;
    const float mc = emc[e];
    const float mf = 1.f - mc;
    const float* xr = x + (size_t)src * DIM + c0;
    const float* er = ea + (size_t)e  * DIM + c0;
    float xv[32], ev[32];
    #pragma unroll
    for (int p = 0; p < 8; p++) {
      float4 u = *(const float4*)(xr + 4*p);
      xv[4*p+0]=u.x; xv[4*p+1]=u.y; xv[4*p+2]=u.z; xv[4*p+3]=u.w;
      float4 w = *(const float4*)(er + 4*p);
      ev[4*p+0]=w.x; ev[4*p+1]=w.y; ev[4*p+2]=w.z; ev[4*p+3]=w.w;
    }
    #pragma unroll
    for (int ci = 0; ci < 32; ci++) {
      const float msg = fmaxf(xv[ci] + ev[ci], 0.f);
      const int cph = (ci + ld) & 31;                  // rotate to spread LDS banks
      atomicAdd(&accC[ld][cph], msg * mc);
      atomicAdd(&accF[ld][cph], msg * mf);
    }
  }
  __syncthreads();
  for (int i = tid; i < NNODE*32; i += 256) {
    const int n = i >> 5, c = i & 31;
    const int cph = (c + n) & 31;
    atomicAdd(&aggrC[((size_t)(b*NNODE + n))*DIM + c0 + c], accC[n][cph]);
    atomicAdd(&aggrF[((size_t)(b*NNODE + n))*DIM + c0 + c], accF[n][cph]);
  }
}

// ---------------- BatchNorm stats (2-stage, deterministic) ----------------
__global__ __launch_bounds__(128) void bn_part_k(
    const float* X0, const float* X1, const float* X2, const float* X3,
    float* __restrict__ psum, float* __restrict__ psq)
{
  const int ti = blockIdx.y, chunk = blockIdx.x, col = threadIdx.x;
  const float* X = (ti == 0) ? X0 : (ti == 1) ? X1 : (ti == 2) ? X2 : X3;
  const float* p = X + (size_t)chunk * 256 * DIM + col;
  float s = 0.f, sq = 0.f;
  for (int r = 0; r < 256; r++) {
    const float xv = p[(size_t)r * DIM];
    s += xv; sq += xv * xv;
  }
  psum[(ti*32 + chunk)*DIM + col] = s;
  psq [(ti*32 + chunk)*DIM + col] = sq;
}

__global__ __launch_bounds__(128) void bn_final_k(
    const float* __restrict__ psum, const float* __restrict__ psq,
    const float* g0, const float* g1, const float* g2, const float* g3,
    const float* b0, const float* b1, const float* b2, const float* b3,
    float2* __restrict__ ss)
{
  const int ti = blockIdx.x, col = threadIdx.x;
  const float* g = (ti == 0) ? g0 : (ti == 1) ? g1 : (ti == 2) ? g2 : g3;
  const float* bb = (ti == 0) ? b0 : (ti == 1) ? b1 : (ti == 2) ? b2 : b3;
  float s = 0.f, sq = 0.f;
  for (int c = 0; c < 32; c++) { s += psum[(ti*32 + c)*DIM + col]; sq += psq[(ti*32 + c)*DIM + col]; }
  const float mean = s * (1.f/8192.f);
  const float var  = sq * (1.f/8192.f) - mean*mean;
  const float istd = rsqrtf(var + 1e-5f);
  const float scale = g[col] * istd;
  ss[ti*DIM + col] = make_float2(scale, bb[col] - mean*scale);
}

// ---------------- Final outputs ----------------
__global__ __launch_bounds__(256) void final_k(
    const float* __restrict__ fmc, const float* __restrict__ fmf,
    const float2* __restrict__ ssc, const float2* __restrict__ ssf,
    float* __restrict__ dout)
{
  const int idx4 = blockIdx.x * 256 + threadIdx.x;   // 0..262143
  const int base = idx4 * 4;
  const int col = base & 127;
  const float4 a = *(const float4*)(fmc + base);
  const float4 b = *(const float4*)(fmf + base);
  const float2 s0 = ssc[col], s1 = ssc[col+1], s2 = ssc[col+2], s3 = ssc[col+3];
  const float2 t0 = ssf[col], t1 = ssf[col+1], t2 = ssf[col+2], t3 = ssf[col+3];
  const float c0 = a.x*s0.x + s0.y, c1 = a.y*s1.x + s1.y, c2 = a.z*s2.x + s2.y, c3 = a.w*s3.x + s3.y;
  const float f0 = b.x*t0.x + t0.y, f1 = b.y*t1.x + t1.y, f2 = b.z*t2.x + t2.y, f3 = b.w*t3.x + t3.y;
  *(float4*)(dout + 1048576 + base) = make_float4(c0,c1,c2,c3);
  *(float4*)(dout + 2097152 + base) = make_float4(f0,f1,f2,f3);
  *(float4*)(dout + base) = make_float4(0.5f*(c0+f0), 0.5f*(c1+f1), 0.5f*(c2+f2), 0.5f*(c3+f3));
}

// ---------------- Launcher ----------------
extern "C" void kernel_launch(void* const* d_in, const int* in_sizes, int n_in,
                              void* d_out, int out_size, void* d_ws, size_t ws_size,
                              hipStream_t stream)
{
  const float* x    = (const float*)d_in[0];
  const int*   ei   = (const int*)  d_in[2];
  const float* ea   = (const float*)d_in[3];
  const float* temp = (const float*)d_in[4];
  const float* cenc = (const float*)d_in[5];
  const float* fenc = (const float*)d_in[6];
  const float* Wq   = (const float*)d_in[7];
  const float* bq_v = (const float*)d_in[8];
  const float* Wk   = (const float*)d_in[9];
  const float* bk_v = (const float*)d_in[10];
  const float* Wv   = (const float*)d_in[11];
  const float* bv_v = (const float*)d_in[12];
  const float* Wo   = (const float*)d_in[13];
  const float* bo_v = (const float*)d_in[14];
  const float* Wg1  = (const float*)d_in[15];
  const float* bg1v = (const float*)d_in[16];
  const float* Wg2  = (const float*)d_in[17];
  const float* bg2v = (const float*)d_in[18];
  const float* Wam  = (const float*)d_in[19];
  const float* bamv = (const float*)d_in[20];
  const float* Wm1  = (const float*)d_in[21];
  const float* bm1v = (const float*)d_in[22];
  const float* Wm2  = (const float*)d_in[23];
  const float* bm2v = (const float*)d_in[24];
  const float* g_attn  = (const float*)d_in[25];
  const float* be_attn = (const float*)d_in[26];
  const float* g_mpnn  = (const float*)d_in[27];
  const float* be_mpnn = (const float*)d_in[28];
  const float* g_mlp   = (const float*)d_in[29];
  const float* be_mlp  = (const float*)d_in[30];

  float* out = (float*)d_out;
  float* ws  = (float*)d_ws;
  const size_t M1 = 1048576;

  float* q    = ws + 0*M1;
  float* kbuf = ws + 1*M1;
  float* vbuf = ws + 2*M1;
  float* fcp  = ws + 3*M1;
  float* ffp  = ws + 4*M1;
  float* acr  = ws + 5*M1;
  float* afr  = ws + 6*M1;
  float* agc  = ws + 7*M1;
  float* agf  = ws + 8*M1;
  float* ghc  = ws + 9*M1;    // 2M
  float* ghf  = ws + 11*M1;   // 2M
  float* emc  = ws + 13*M1;   // 262144
  float* psum = ws + 13*M1 + 262144;   // 16384
  float* psq  = psum + 16384;          // 16384
  float2* ss  = (float2*)(psq + 16384);
  // reuses (sequenced by stream order)
  float* mcr = q;
  float* mfr = kbuf;
  float* fC  = vbuf;
  float* fF  = fcp;
  float* fhc = ghc;
  float* fhf = ghf;
  float* fmc = ffp;
  float* fmf = agc;

  hipMemsetAsync(agc, 0, 2*M1*sizeof(float), stream);

  const dim3 blk(256);

  // QKV projections
  {
    GemmJob jq{x, nullptr, nullptr, nullptr, Wq, bq_v, nullptr, q};
    GemmJob jk{x, nullptr, nullptr, nullptr, Wk, bk_v, nullptr, kbuf};
    GemmJob jv{x, nullptr, nullptr, nullptr, Wv, bv_v, nullptr, vbuf};
    gemm_k<0,0,0><<<dim3(2,128,3), blk, 0, stream>>>(jq, jk, jv, TTOK, 128, 128);
  }
  // Fused attention + entropy
  attn_k<<<dim3(256), blk, 0, stream>>>(q, kbuf, vbuf, temp, fcp, ffp, out);
  // Edge sigmoid masks
  edge_k<<<dim3(8192), blk, 0, stream>>>(q, kbuf, ei, out + 3408384, emc);
  // GINE aggregation
  gine_aggr_k<<<dim3(4,32,2), blk, 0, stream>>>(x, ea, ei, emc, agc, agf);
  // Wo projection
  {
    GemmJob j0{fcp, nullptr, nullptr, nullptr, Wo, bo_v, nullptr, acr};
    GemmJob j1{ffp, nullptr, nullptr, nullptr, Wo, bo_v, nullptr, afr};
    gemm_k<0,0,0><<<dim3(2,128,2), blk, 0, stream>>>(j0, j1, j0, TTOK, 128, 128);
  }
  // GINE layer 1 (h = x + aggr, relu)
  {
    GemmJob j0{x, agc, nullptr, nullptr, Wg1, bg1v, nullptr, ghc};
    GemmJob j1{x, agf, nullptr, nullptr, Wg1, bg1v, nullptr, ghf};
    gemm_k<1,1,0><<<dim3(4,128,2), blk, 0, stream>>>(j0, j1, j0, TTOK, 256, 128);
  }
  // GINE layer 2
  {
    GemmJob j0{ghc, nullptr, nullptr, nullptr, Wg2, bg2v, nullptr, mcr};
    GemmJob j1{ghf, nullptr, nullptr, nullptr, Wg2, bg2v, nullptr, mfr};
    gemm_k<0,0,0><<<dim3(2,128,2), blk, 0, stream>>>(j0, j1, j0, TTOK, 128, 256);
  }
  // BN stats round 1: acr, afr, mcr, mfr
  bn_part_k<<<dim3(32,4), dim3(128), 0, stream>>>(acr, afr, mcr, mfr, psum, psq);
  bn_final_k<<<dim3(4), dim3(128), 0, stream>>>(psum, psq,
      g_attn, g_attn, g_mpnn, g_mpnn, be_attn, be_attn, be_mpnn, be_mpnn, ss);
  // Fuse linear: concat(bn(attn), bn(mpnn)) @ Wam + bam
  {
    GemmJob j0{acr, mcr, ss + 0,   ss + 256, Wam, bamv, nullptr, fC};
    GemmJob j1{afr, mfr, ss + 128, ss + 384, Wam, bamv, nullptr, fF};
    gemm_k<2,0,0><<<dim3(2,128,2), blk, 0, stream>>>(j0, j1, j0, TTOK, 128, 256);
  }
  // Fuse MLP layer 1 (relu)
  {
    GemmJob j0{fC, nullptr, nullptr, nullptr, Wm1, bm1v, nullptr, fhc};
    GemmJob j1{fF, nullptr, nullptr, nullptr, Wm1, bm1v, nullptr, fhf};
    gemm_k<0,1,0><<<dim3(4,128,2), blk, 0, stream>>>(j0, j1, j0, TTOK, 256, 128);
  }
  // Fuse MLP layer 2 + residual f
  {
    GemmJob j0{fhc, nullptr, nullptr, nullptr, Wm2, bm2v, fC, fmc};
    GemmJob j1{fhf, nullptr, nullptr, nullptr, Wm2, bm2v, fF, fmf};
    gemm_k<0,0,1><<<dim3(2,128,2), blk, 0, stream>>>(j0, j1, j0, TTOK, 128, 256);
  }
  // BN stats round 2: fmc, fmf
  bn_part_k<<<dim3(32,2), dim3(128), 0, stream>>>(fmc, fmf, fmc, fmc, psum, psq);
  bn_final_k<<<dim3(2), dim3(128), 0, stream>>>(psum, psq,
      g_mlp, g_mlp, g_mlp, g_mlp, be_mlp, be_mlp, be_mlp, be_mlp, ss + 512);
  // Final features + new_x
  final_k<<<dim3(1024), blk, 0, stream>>>(fmc, fmf, ss + 512, ss + 640, out);
  // Pass-through encodings
  hipMemcpyAsync(out + 3146240, (const void*)cenc, 131072*sizeof(float),
                 hipMemcpyDeviceToDevice, stream);
  hipMemcpyAsync(out + 3277312, (const void*)fenc, 131072*sizeof(float),
                 hipMemcpyDeviceToDevice, stream);
}

// Round 2
// 550.981 us; speedup vs baseline: 1.4780x; 1.4780x over previous
//
#include <hip/hip_runtime.h>

#define TTOK   8192
#define BGR    32
#define NNODE  256
#define DIM    128
#define NH     8
#define HD     16
#define NEDGE  262144
#define SCALE_QK 0.25f

// ---------------- GEMM ----------------
struct GemmJob {
  const float*  A1;
  const float*  A2;
  const float2* ss1;
  const float2* ss2;
  const float*  W;
  const float*  bias;
  const float*  res;
  float*        C;
};

// AMODE: 0 = A1 (lda=K); 1 = A1+A2 (both [M,128]); 2 = concat(bn(A1,ss1), bn(A2,ss2)) K=256
template<int AMODE, int RELU, int HASRES>
__global__ __launch_bounds__(256) void gemm_k(GemmJob j0, GemmJob j1, GemmJob j2,
                                              int M, int N, int K)
{
  const GemmJob jb = (blockIdx.z == 0) ? j0 : ((blockIdx.z == 1) ? j1 : j2);
  __shared__ float As[32][68];   // [k][m], transposed
  __shared__ float Ws[32][68];   // [k][n]
  const int bm = blockIdx.y * 64;
  const int bn = blockIdx.x * 64;
  const int tid = threadIdx.x;
  const int tx = tid & 15, ty = tid >> 4;
  const int r0 = ty * 4, c0 = tx * 4;
  float acc00=0,acc01=0,acc02=0,acc03=0;
  float acc10=0,acc11=0,acc12=0,acc13=0;
  float acc20=0,acc21=0,acc22=0,acc23=0;
  float acc30=0,acc31=0,acc32=0,acc33=0;

  for (int bk = 0; bk < K; bk += 32) {
    // A tile 64x32 -> As (transposed)
    {
      const int rbase = tid >> 3;
      const int kg = (tid & 7) * 4;
      #pragma unroll
      for (int half = 0; half < 2; half++) {
        const int rr = rbase + half * 32;
        const int row = bm + rr;
        const int k0 = bk + kg;
        float4 a;
        if (AMODE == 0) {
          a = *(const float4*)(jb.A1 + (size_t)row * K + k0);
        } else if (AMODE == 1) {
          float4 u = *(const float4*)(jb.A1 + (size_t)row * 128 + k0);
          float4 w = *(const float4*)(jb.A2 + (size_t)row * 128 + k0);
          a = make_float4(u.x + w.x, u.y + w.y, u.z + w.z, u.w + w.w);
        } else {
          if (k0 < 128) {
            float4 u = *(const float4*)(jb.A1 + (size_t)row * 128 + k0);
            float2 s0 = jb.ss1[k0], s1 = jb.ss1[k0+1], s2 = jb.ss1[k0+2], s3 = jb.ss1[k0+3];
            a = make_float4(u.x*s0.x+s0.y, u.y*s1.x+s1.y, u.z*s2.x+s2.y, u.w*s3.x+s3.y);
          } else {
            const int kq = k0 - 128;
            float4 u = *(const float4*)(jb.A2 + (size_t)row * 128 + kq);
            float2 s0 = jb.ss2[kq], s1 = jb.ss2[kq+1], s2 = jb.ss2[kq+2], s3 = jb.ss2[kq+3];
            a = make_float4(u.x*s0.x+s0.y, u.y*s1.x+s1.y, u.z*s2.x+s2.y, u.w*s3.x+s3.y);
          }
        }
        As[kg+0][rr] = a.x; As[kg+1][rr] = a.y; As[kg+2][rr] = a.z; As[kg+3][rr] = a.w;
      }
    }
    // W tile 32x64
    {
      const int kb = tid >> 4;
      const int cg = (tid & 15) * 4;
      #pragma unroll
      for (int half = 0; half < 2; half++) {
        const int kk2 = kb + half * 16;
        float4 w = *(const float4*)(jb.W + (size_t)(bk + kk2) * N + bn + cg);
        *(float4*)&Ws[kk2][cg] = w;
      }
    }
    __syncthreads();
    #pragma unroll
    for (int kk = 0; kk < 32; kk++) {
      const float4 av = *(const float4*)&As[kk][r0];
      const float4 bv = *(const float4*)&Ws[kk][c0];
      const float a0 = av.x, a1 = av.y, a2 = av.z, a3 = av.w;
      const float b0 = bv.x, b1 = bv.y, b2 = bv.z, b3 = bv.w;
      acc00 = fmaf(a0,b0,acc00); acc01 = fmaf(a0,b1,acc01); acc02 = fmaf(a0,b2,acc02); acc03 = fmaf(a0,b3,acc03);
      acc10 = fmaf(a1,b0,acc10); acc11 = fmaf(a1,b1,acc11); acc12 = fmaf(a1,b2,acc12); acc13 = fmaf(a1,b3,acc13);
      acc20 = fmaf(a2,b0,acc20); acc21 = fmaf(a2,b1,acc21); acc22 = fmaf(a2,b2,acc22); acc23 = fmaf(a2,b3,acc23);
      acc30 = fmaf(a3,b0,acc30); acc31 = fmaf(a3,b1,acc31); acc32 = fmaf(a3,b2,acc32); acc33 = fmaf(a3,b3,acc33);
    }
    __syncthreads();
  }

  const float bb0 = jb.bias[bn+c0+0], bb1 = jb.bias[bn+c0+1], bb2 = jb.bias[bn+c0+2], bb3 = jb.bias[bn+c0+3];
  #pragma unroll
  for (int i = 0; i < 4; i++) {
    const int row = bm + r0 + i;
    float o0, o1, o2, o3;
    if (i == 0) { o0=acc00; o1=acc01; o2=acc02; o3=acc03; }
    else if (i == 1) { o0=acc10; o1=acc11; o2=acc12; o3=acc13; }
    else if (i == 2) { o0=acc20; o1=acc21; o2=acc22; o3=acc23; }
    else { o0=acc30; o1=acc31; o2=acc32; o3=acc33; }
    o0 += bb0; o1 += bb1; o2 += bb2; o3 += bb3;
    if (RELU) { o0 = fmaxf(o0,0.f); o1 = fmaxf(o1,0.f); o2 = fmaxf(o2,0.f); o3 = fmaxf(o3,0.f); }
    if (HASRES) {
      float4 r = *(const float4*)(jb.res + (size_t)row * N + bn + c0);
      o0 += r.x; o1 += r.y; o2 += r.z; o3 += r.w;
    }
    *(float4*)(jb.C + (size_t)row * N + bn + c0) = make_float4(o0,o1,o2,o3);
  }
}

// ---------------- Fused attention (per (b,h) block) ----------------
__global__ __launch_bounds__(256) void attn_k(
    const float* __restrict__ q, const float* __restrict__ k, const float* __restrict__ v,
    const float* __restrict__ tptr, float* __restrict__ fc, float* __restrict__ ff,
    float* __restrict__ dout)
{
  const int bh = blockIdx.x;
  const int b = bh >> 3, h = bh & 7;
  __shared__ float kT[16][260];
  __shared__ float vT[16][260];
  __shared__ float entw[4][2];
  const int tid = threadIdx.x;
  {
    const int j = tid;
    const float* kr = k + ((size_t)(b*NNODE + j))*DIM + h*HD;
    const float* vr = v + ((size_t)(b*NNODE + j))*DIM + h*HD;
    #pragma unroll
    for (int p = 0; p < 4; p++) {
      float4 kv = *(const float4*)(kr + 4*p);
      kT[4*p+0][j] = kv.x; kT[4*p+1][j] = kv.y; kT[4*p+2][j] = kv.z; kT[4*p+3][j] = kv.w;
      float4 vv = *(const float4*)(vr + 4*p);
      vT[4*p+0][j] = vv.x; vT[4*p+1][j] = vv.y; vT[4*p+2][j] = vv.z; vT[4*p+3][j] = vv.w;
    }
  }
  __syncthreads();
  const float sc = SCALE_QK / tptr[0];
  const int wv = tid >> 6, lane = tid & 63;
  float entc = 0.f, entf = 0.f;

  for (int i0 = wv*2; i0 < NNODE; i0 += 8) {
    const float* q0r = q + ((size_t)(b*NNODE + i0))*DIM + h*HD;
    float qa[16], qb[16];
    #pragma unroll
    for (int p = 0; p < 4; p++) {
      float4 a = *(const float4*)(q0r + 4*p);
      qa[4*p+0]=a.x; qa[4*p+1]=a.y; qa[4*p+2]=a.z; qa[4*p+3]=a.w;
      float4 c = *(const float4*)(q0r + DIM + 4*p);
      qb[4*p+0]=c.x; qb[4*p+1]=c.y; qb[4*p+2]=c.z; qb[4*p+3]=c.w;
    }
    float s0[4] = {0,0,0,0}, s1[4] = {0,0,0,0};
    #pragma unroll
    for (int d = 0; d < 16; d++) {
      const float4 kv = *(const float4*)&kT[d][lane*4];
      s0[0] = fmaf(qa[d], kv.x, s0[0]); s0[1] = fmaf(qa[d], kv.y, s0[1]);
      s0[2] = fmaf(qa[d], kv.z, s0[2]); s0[3] = fmaf(qa[d], kv.w, s0[3]);
      s1[0] = fmaf(qb[d], kv.x, s1[0]); s1[1] = fmaf(qb[d], kv.y, s1[1]);
      s1[2] = fmaf(qb[d], kv.z, s1[2]); s1[3] = fmaf(qb[d], kv.w, s1[3]);
    }
    #pragma unroll
    for (int m = 0; m < 4; m++) { s0[m] *= sc; s1[m] *= sc; }

    float mx0 = fmaxf(fmaxf(s0[0],s0[1]),fmaxf(s0[2],s0[3]));
    float mn0 = fminf(fminf(s0[0],s0[1]),fminf(s0[2],s0[3]));
    float mx1 = fmaxf(fmaxf(s1[0],s1[1]),fmaxf(s1[2],s1[3]));
    float mn1 = fminf(fminf(s1[0],s1[1]),fminf(s1[2],s1[3]));
    #pragma unroll
    for (int off = 1; off < 64; off <<= 1) {
      mx0 = fmaxf(mx0, __shfl_xor(mx0, off)); mn0 = fminf(mn0, __shfl_xor(mn0, off));
      mx1 = fmaxf(mx1, __shfl_xor(mx1, off)); mn1 = fminf(mn1, __shfl_xor(mn1, off));
    }
    float ec0[4], ef0[4], ec1[4], ef1[4];
    float zc0=0,zf0=0,zc1=0,zf1=0;
    #pragma unroll
    for (int m = 0; m < 4; m++) {
      ec0[m] = __expf(s0[m]-mx0); zc0 += ec0[m];
      ef0[m] = __expf(mn0-s0[m]); zf0 += ef0[m];
      ec1[m] = __expf(s1[m]-mx1); zc1 += ec1[m];
      ef1[m] = __expf(mn1-s1[m]); zf1 += ef1[m];
    }
    #pragma unroll
    for (int off = 1; off < 64; off <<= 1) {
      zc0 += __shfl_xor(zc0, off); zf0 += __shfl_xor(zf0, off);
      zc1 += __shfl_xor(zc1, off); zf1 += __shfl_xor(zf1, off);
    }
    const float rc0 = 1.f/zc0, rf0 = 1.f/zf0, rc1 = 1.f/zc1, rf1 = 1.f/zf1;
    #pragma unroll
    for (int m = 0; m < 4; m++) {
      float p;
      p = fminf(fmaxf(ec0[m]*rc0, 1e-10f), 1.f-1e-10f); entc -= p*__logf(p);
      p = fminf(fmaxf(ef0[m]*rf0, 1e-10f), 1.f-1e-10f); entf -= p*__logf(p);
      p = fminf(fmaxf(ec1[m]*rc1, 1e-10f), 1.f-1e-10f); entc -= p*__logf(p);
      p = fminf(fmaxf(ef1[m]*rf1, 1e-10f), 1.f-1e-10f); entf -= p*__logf(p);
    }
    float o0c[16], o0f[16], o1c[16], o1f[16];
    #pragma unroll
    for (int d = 0; d < 16; d++) {
      const float4 vv = *(const float4*)&vT[d][lane*4];
      o0c[d] = ec0[0]*vv.x + ec0[1]*vv.y + ec0[2]*vv.z + ec0[3]*vv.w;
      o0f[d] = ef0[0]*vv.x + ef0[1]*vv.y + ef0[2]*vv.z + ef0[3]*vv.w;
      o1c[d] = ec1[0]*vv.x + ec1[1]*vv.y + ec1[2]*vv.z + ec1[3]*vv.w;
      o1f[d] = ef1[0]*vv.x + ef1[1]*vv.y + ef1[2]*vv.z + ef1[3]*vv.w;
    }
    #pragma unroll
    for (int off = 1; off < 64; off <<= 1) {
      #pragma unroll
      for (int d = 0; d < 16; d++) {
        o0c[d] += __shfl_xor(o0c[d], off);
        o0f[d] += __shfl_xor(o0f[d], off);
        o1c[d] += __shfl_xor(o1c[d], off);
        o1f[d] += __shfl_xor(o1f[d], off);
      }
    }
    if (lane == 0) {
      float* p0c = fc + ((size_t)(b*NNODE + i0))*DIM + h*HD;
      float* p0f = ff + ((size_t)(b*NNODE + i0))*DIM + h*HD;
      float* p1c = p0c + DIM;
      float* p1f = p0f + DIM;
      *(float4*)(p0c+0)  = make_float4(o0c[0]*rc0,  o0c[1]*rc0,  o0c[2]*rc0,  o0c[3]*rc0);
      *(float4*)(p0c+4)  = make_float4(o0c[4]*rc0,  o0c[5]*rc0,  o0c[6]*rc0,  o0c[7]*rc0);
      *(float4*)(p0c+8)  = make_float4(o0c[8]*rc0,  o0c[9]*rc0,  o0c[10]*rc0, o0c[11]*rc0);
      *(float4*)(p0c+12) = make_float4(o0c[12]*rc0, o0c[13]*rc0, o0c[14]*rc0, o0c[15]*rc0);
      *(float4*)(p0f+0)  = make_float4(o0f[0]*rf0,  o0f[1]*rf0,  o0f[2]*rf0,  o0f[3]*rf0);
      *(float4*)(p0f+4)  = make_float4(o0f[4]*rf0,  o0f[5]*rf0,  o0f[6]*rf0,  o0f[7]*rf0);
      *(float4*)(p0f+8)  = make_float4(o0f[8]*rf0,  o0f[9]*rf0,  o0f[10]*rf0, o0f[11]*rf0);
      *(float4*)(p0f+12) = make_float4(o0f[12]*rf0, o0f[13]*rf0, o0f[14]*rf0, o0f[15]*rf0);
      *(float4*)(p1c+0)  = make_float4(o1c[0]*rc1,  o1c[1]*rc1,  o1c[2]*rc1,  o1c[3]*rc1);
      *(float4*)(p1c+4)  = make_float4(o1c[4]*rc1,  o1c[5]*rc1,  o1c[6]*rc1,  o1c[7]*rc1);
      *(float4*)(p1c+8)  = make_float4(o1c[8]*rc1,  o1c[9]*rc1,  o1c[10]*rc1, o1c[11]*rc1);
      *(float4*)(p1c+12) = make_float4(o1c[12]*rc1, o1c[13]*rc1, o1c[14]*rc1, o1c[15]*rc1);
      *(float4*)(p1f+0)  = make_float4(o1f[0]*rf1,  o1f[1]*rf1,  o1f[2]*rf1,  o1f[3]*rf1);
      *(float4*)(p1f+4)  = make_float4(o1f[4]*rf1,  o1f[5]*rf1,  o1f[6]*rf1,  o1f[7]*rf1);
      *(float4*)(p1f+8)  = make_float4(o1f[8]*rf1,  o1f[9]*rf1,  o1f[10]*rf1, o1f[11]*rf1);
      *(float4*)(p1f+12) = make_float4(o1f[12]*rf1, o1f[13]*rf1, o1f[14]*rf1, o1f[15]*rf1);
    }
  }
  #pragma unroll
  for (int off = 1; off < 64; off <<= 1) {
    entc += __shfl_xor(entc, off);
    entf += __shfl_xor(entf, off);
  }
  if (lane == 0) { entw[wv][0] = entc; entw[wv][1] = entf; }
  __syncthreads();
  if (tid == 0) {
    const float tc = entw[0][0]+entw[1][0]+entw[2][0]+entw[3][0];
    const float tf = entw[0][1]+entw[1][1]+entw[2][1]+entw[3][1];
    dout[3145728 + bh] = tc * (1.0f/256.0f);
    dout[3145984 + bh] = tf * (1.0f/256.0f);
  }
}

// ---------------- Edge sigmoid mask (one thread per (edge, head)) + dst histogram ----------------
__global__ __launch_bounds__(256) void edge_k(
    const float* __restrict__ q, const float* __restrict__ k,
    const int* __restrict__ ei, float* __restrict__ maskout, float* __restrict__ emc,
    int* __restrict__ cnt)
{
  const int gt = blockIdx.x * 256 + threadIdx.x;   // 0 .. E*8-1
  const int e = gt >> 3, h = gt & 7;
  const int src = ei[e];
  const int dst = ei[NEDGE + e];
  const float* qr = q + (size_t)src * DIM + h*HD;
  const float* kr = k + (size_t)dst * DIM + h*HD;
  float s = 0.f;
  #pragma unroll
  for (int p = 0; p < 4; p++) {
    float4 a = *(const float4*)(qr + 4*p);
    float4 c = *(const float4*)(kr + 4*p);
    s += a.x*c.x + a.y*c.y + a.z*c.z + a.w*c.w;
  }
  s *= SCALE_QK;
  const float sig = 1.f / (1.f + __expf(-s));
  maskout[gt] = sig;
  float m = sig;
  m += __shfl_xor(m, 1); m += __shfl_xor(m, 2); m += __shfl_xor(m, 4);
  if ((threadIdx.x & 7) == 0) {
    emc[e] = m * 0.125f;
    atomicAdd(&cnt[dst], 1);
  }
}

// ---------------- CSR build: exclusive scan over 8192 dst counters ----------------
__global__ __launch_bounds__(256) void scan_k(const int* __restrict__ cnt,
                                              int* __restrict__ off,
                                              int* __restrict__ cursor)
{
  __shared__ int part[256];
  const int t = threadIdx.x;
  const int base = t * 32;
  int local[32];
  int s = 0;
  #pragma unroll
  for (int i = 0; i < 32; i++) { local[i] = s; s += cnt[base + i]; }
  part[t] = s;
  __syncthreads();
  int pre = 0;
  for (int i = 0; i < t; i++) pre += part[i];
  #pragma unroll
  for (int i = 0; i < 32; i++) {
    const int v = pre + local[i];
    off[base + i] = v;
    cursor[base + i] = v;
  }
  if (t == 255) off[8192] = pre + s;
}

__global__ __launch_bounds__(256) void place_k(const int* __restrict__ ei,
                                               int* __restrict__ cursor,
                                               int* __restrict__ elist)
{
  const int e = blockIdx.x * 256 + threadIdx.x;
  const int d = ei[NEDGE + e];
  const int pos = atomicAdd(&cursor[d], 1);
  elist[pos] = e;
}

// ---------------- GINE gather-aggregate (CSR, no atomics, no LDS) ----------------
__global__ __launch_bounds__(256) void gine_gather_k(
    const float* __restrict__ x, const float* __restrict__ ea,
    const int* __restrict__ ei, const float* __restrict__ emc,
    const int* __restrict__ off, const int* __restrict__ elist,
    float* __restrict__ aggrC, float* __restrict__ aggrF)
{
  const int warp = threadIdx.x >> 6, lane = threadIdx.x & 63;
  const int half = lane >> 5, c = lane & 31;
  const int n = blockIdx.x * 8 + warp * 2 + half;   // node 0..8191
  const int c4 = c * 4;
  float4 aC = make_float4(0,0,0,0), aF = make_float4(0,0,0,0);
  int i = off[n];
  const int end = off[n + 1];
  if (i < end) {
    int e = elist[i];
    int s = ei[e];
    float mc = emc[e];
    for (;;) {
      const float4 u = *(const float4*)(x  + (size_t)s * DIM + c4);
      const float4 w = *(const float4*)(ea + (size_t)e * DIM + c4);
      int en = 0, sn = 0; float mcn = 0.f;
      if (i + 1 < end) { en = elist[i + 1]; sn = ei[en]; mcn = emc[en]; }
      const float mf = 1.f - mc;
      const float m0 = fmaxf(u.x + w.x, 0.f);
      const float m1 = fmaxf(u.y + w.y, 0.f);
      const float m2 = fmaxf(u.z + w.z, 0.f);
      const float m3 = fmaxf(u.w + w.w, 0.f);
      aC.x = fmaf(m0, mc, aC.x); aC.y = fmaf(m1, mc, aC.y);
      aC.z = fmaf(m2, mc, aC.z); aC.w = fmaf(m3, mc, aC.w);
      aF.x = fmaf(m0, mf, aF.x); aF.y = fmaf(m1, mf, aF.y);
      aF.z = fmaf(m2, mf, aF.z); aF.w = fmaf(m3, mf, aF.w);
      i++;
      if (i >= end) break;
      e = en; s = sn; mc = mcn;
    }
  }
  *(float4*)(aggrC + (size_t)n * DIM + c4) = aC;
  *(float4*)(aggrF + (size_t)n * DIM + c4) = aF;
}

// ---------------- BatchNorm stats (2-stage, deterministic) ----------------
__global__ __launch_bounds__(128) void bn_part_k(
    const float* X0, const float* X1, const float* X2, const float* X3,
    float* __restrict__ psum, float* __restrict__ psq)
{
  const int ti = blockIdx.y, chunk = blockIdx.x, col = threadIdx.x;
  const float* X = (ti == 0) ? X0 : (ti == 1) ? X1 : (ti == 2) ? X2 : X3;
  const float* p = X + (size_t)chunk * 256 * DIM + col;
  float s = 0.f, sq = 0.f;
  for (int r = 0; r < 256; r++) {
    const float xv = p[(size_t)r * DIM];
    s += xv; sq += xv * xv;
  }
  psum[(ti*32 + chunk)*DIM + col] = s;
  psq [(ti*32 + chunk)*DIM + col] = sq;
}

__global__ __launch_bounds__(128) void bn_final_k(
    const float* __restrict__ psum, const float* __restrict__ psq,
    const float* g0, const float* g1, const float* g2, const float* g3,
    const float* b0, const float* b1, const float* b2, const float* b3,
    float2* __restrict__ ss)
{
  const int ti = blockIdx.x, col = threadIdx.x;
  const float* g = (ti == 0) ? g0 : (ti == 1) ? g1 : (ti == 2) ? g2 : g3;
  const float* bb = (ti == 0) ? b0 : (ti == 1) ? b1 : (ti == 2) ? b2 : b3;
  float s = 0.f, sq = 0.f;
  for (int c = 0; c < 32; c++) { s += psum[(ti*32 + c)*DIM + col]; sq += psq[(ti*32 + c)*DIM + col]; }
  const float mean = s * (1.f/8192.f);
  const float var  = sq * (1.f/8192.f) - mean*mean;
  const float istd = rsqrtf(var + 1e-5f);
  const float scale = g[col] * istd;
  ss[ti*DIM + col] = make_float2(scale, bb[col] - mean*scale);
}

// ---------------- Final outputs ----------------
__global__ __launch_bounds__(256) void final_k(
    const float* __restrict__ fmc, const float* __restrict__ fmf,
    const float2* __restrict__ ssc, const float2* __restrict__ ssf,
    float* __restrict__ dout)
{
  const int idx4 = blockIdx.x * 256 + threadIdx.x;   // 0..262143
  const int base = idx4 * 4;
  const int col = base & 127;
  const float4 a = *(const float4*)(fmc + base);
  const float4 b = *(const float4*)(fmf + base);
  const float2 s0 = ssc[col], s1 = ssc[col+1], s2 = ssc[col+2], s3 = ssc[col+3];
  const float2 t0 = ssf[col], t1 = ssf[col+1], t2 = ssf[col+2], t3 = ssf[col+3];
  const float c0 = a.x*s0.x + s0.y, c1 = a.y*s1.x + s1.y, c2 = a.z*s2.x + s2.y, c3 = a.w*s3.x + s3.y;
  const float f0 = b.x*t0.x + t0.y, f1 = b.y*t1.x + t1.y, f2 = b.z*t2.x + t2.y, f3 = b.w*t3.x + t3.y;
  *(float4*)(dout + 1048576 + base) = make_float4(c0,c1,c2,c3);
  *(float4*)(dout + 2097152 + base) = make_float4(f0,f1,f2,f3);
  *(float4*)(dout + base) = make_float4(0.5f*(c0+f0), 0.5f*(c1+f1), 0.5f*(c2+f2), 0.5f*(c3+f3));
}

// ---------------- Launcher ----------------
extern "C" void kernel_launch(void* const* d_in, const int* in_sizes, int n_in,
                              void* d_out, int out_size, void* d_ws, size_t ws_size,
                              hipStream_t stream)
{
  const float* x    = (const float*)d_in[0];
  const int*   ei   = (const int*)  d_in[2];
  const float* ea   = (const float*)d_in[3];
  const float* temp = (const float*)d_in[4];
  const float* cenc = (const float*)d_in[5];
  const float* fenc = (const float*)d_in[6];
  const float* Wq   = (const float*)d_in[7];
  const float* bq_v = (const float*)d_in[8];
  const float* Wk   = (const float*)d_in[9];
  const float* bk_v = (const float*)d_in[10];
  const float* Wv   = (const float*)d_in[11];
  const float* bv_v = (const float*)d_in[12];
  const float* Wo   = (const float*)d_in[13];
  const float* bo_v = (const float*)d_in[14];
  const float* Wg1  = (const float*)d_in[15];
  const float* bg1v = (const float*)d_in[16];
  const float* Wg2  = (const float*)d_in[17];
  const float* bg2v = (const float*)d_in[18];
  const float* Wam  = (const float*)d_in[19];
  const float* bamv = (const float*)d_in[20];
  const float* Wm1  = (const float*)d_in[21];
  const float* bm1v = (const float*)d_in[22];
  const float* Wm2  = (const float*)d_in[23];
  const float* bm2v = (const float*)d_in[24];
  const float* g_attn  = (const float*)d_in[25];
  const float* be_attn = (const float*)d_in[26];
  const float* g_mpnn  = (const float*)d_in[27];
  const float* be_mpnn = (const float*)d_in[28];
  const float* g_mlp   = (const float*)d_in[29];
  const float* be_mlp  = (const float*)d_in[30];

  float* out = (float*)d_out;
  float* ws  = (float*)d_ws;
  const size_t M1 = 1048576;

  float* q    = ws + 0*M1;
  float* kbuf = ws + 1*M1;
  float* vbuf = ws + 2*M1;
  float* fcp  = ws + 3*M1;
  float* ffp  = ws + 4*M1;
  float* acr  = ws + 5*M1;
  float* afr  = ws + 6*M1;
  float* agc  = ws + 7*M1;
  float* agf  = ws + 8*M1;
  float* ghc  = ws + 9*M1;    // 2M (also CSR ints before GINE1 gemm)
  float* ghf  = ws + 11*M1;   // 2M
  float* emc  = ws + 13*M1;   // 262144
  float* psum = ws + 13*M1 + 262144;   // 16384
  float* psq  = psum + 16384;          // 16384
  float2* ss  = (float2*)(psq + 16384);
  // CSR scratch lives in the ghc region (free until GINE layer-1 gemm)
  int* cnt    = (int*)(ws + 9*M1);     // 8192
  int* off_a  = cnt + 8192;            // 8193
  int* cursor = off_a + 8200;          // 8192
  int* elist  = cursor + 8192;         // 262144
  // reuses (sequenced by stream order)
  float* mcr = q;
  float* mfr = kbuf;
  float* fC  = vbuf;
  float* fF  = fcp;
  float* fhc = ghc;
  float* fhf = ghf;
  float* fmc = ffp;
  float* fmf = agc;

  hipMemsetAsync(cnt, 0, 8192*sizeof(int), stream);

  const dim3 blk(256);

  // QKV projections
  {
    GemmJob jq{x, nullptr, nullptr, nullptr, Wq, bq_v, nullptr, q};
    GemmJob jk{x, nullptr, nullptr, nullptr, Wk, bk_v, nullptr, kbuf};
    GemmJob jv{x, nullptr, nullptr, nullptr, Wv, bv_v, nullptr, vbuf};
    gemm_k<0,0,0><<<dim3(2,128,3), blk, 0, stream>>>(jq, jk, jv, TTOK, 128, 128);
  }
  // Fused attention + entropy
  attn_k<<<dim3(256), blk, 0, stream>>>(q, kbuf, vbuf, temp, fcp, ffp, out);
  // Edge sigmoid masks + dst histogram
  edge_k<<<dim3(8192), blk, 0, stream>>>(q, kbuf, ei, out + 3408384, emc, cnt);
  // CSR build
  scan_k<<<dim3(1), blk, 0, stream>>>(cnt, off_a, cursor);
  place_k<<<dim3(1024), blk, 0, stream>>>(ei, cursor, elist);
  // GINE gather aggregation (no atomics)
  gine_gather_k<<<dim3(1024), blk, 0, stream>>>(x, ea, ei, emc, off_a, elist, agc, agf);
  // Wo projection
  {
    GemmJob j0{fcp, nullptr, nullptr, nullptr, Wo, bo_v, nullptr, acr};
    GemmJob j1{ffp, nullptr, nullptr, nullptr, Wo, bo_v, nullptr, afr};
    gemm_k<0,0,0><<<dim3(2,128,2), blk, 0, stream>>>(j0, j1, j0, TTOK, 128, 128);
  }
  // GINE layer 1 (h = x + aggr, relu)
  {
    GemmJob j0{x, agc, nullptr, nullptr, Wg1, bg1v, nullptr, ghc};
    GemmJob j1{x, agf, nullptr, nullptr, Wg1, bg1v, nullptr, ghf};
    gemm_k<1,1,0><<<dim3(4,128,2), blk, 0, stream>>>(j0, j1, j0, TTOK, 256, 128);
  }
  // GINE layer 2
  {
    GemmJob j0{ghc, nullptr, nullptr, nullptr, Wg2, bg2v, nullptr, mcr};
    GemmJob j1{ghf, nullptr, nullptr, nullptr, Wg2, bg2v, nullptr, mfr};
    gemm_k<0,0,0><<<dim3(2,128,2), blk, 0, stream>>>(j0, j1, j0, TTOK, 128, 256);
  }
  // BN stats round 1: acr, afr, mcr, mfr
  bn_part_k<<<dim3(32,4), dim3(128), 0, stream>>>(acr, afr, mcr, mfr, psum, psq);
  bn_final_k<<<dim3(4), dim3(128), 0, stream>>>(psum, psq,
      g_attn, g_attn, g_mpnn, g_mpnn, be_attn, be_attn, be_mpnn, be_mpnn, ss);
  // Fuse linear: concat(bn(attn), bn(mpnn)) @ Wam + bam
  {
    GemmJob j0{acr, mcr, ss + 0,   ss + 256, Wam, bamv, nullptr, fC};
    GemmJob j1{afr, mfr, ss + 128, ss + 384, Wam, bamv, nullptr, fF};
    gemm_k<2,0,0><<<dim3(2,128,2), blk, 0, stream>>>(j0, j1, j0, TTOK, 128, 256);
  }
  // Fuse MLP layer 1 (relu)
  {
    GemmJob j0{fC, nullptr, nullptr, nullptr, Wm1, bm1v, nullptr, fhc};
    GemmJob j1{fF, nullptr, nullptr, nullptr, Wm1, bm1v, nullptr, fhf};
    gemm_k<0,1,0><<<dim3(4,128,2), blk, 0, stream>>>(j0, j1, j0, TTOK, 256, 128);
  }
  // Fuse MLP layer 2 + residual f
  {
    GemmJob j0{fhc, nullptr, nullptr, nullptr, Wm2, bm2v, fC, fmc};
    GemmJob j1{fhf, nullptr, nullptr, nullptr, Wm2, bm2v, fF, fmf};
    gemm_k<0,0,1><<<dim3(2,128,2), blk, 0, stream>>>(j0, j1, j0, TTOK, 128, 256);
  }
  // BN stats round 2: fmc, fmf
  bn_part_k<<<dim3(32,2), dim3(128), 0, stream>>>(fmc, fmf, fmc, fmc, psum, psq);
  bn_final_k<<<dim3(2), dim3(128), 0, stream>>>(psum, psq,
      g_mlp, g_mlp, g_mlp, g_mlp, be_mlp, be_mlp, be_mlp, be_mlp, ss + 512);
  // Final features + new_x
  final_k<<<dim3(1024), blk, 0, stream>>>(fmc, fmf, ss + 512, ss + 640, out);
  // Pass-through encodings
  hipMemcpyAsync(out + 3146240, (const void*)cenc, 131072*sizeof(float),
                 hipMemcpyDeviceToDevice, stream);
  hipMemcpyAsync(out + 3277312, (const void*)fenc, 131072*sizeof(float),
                 hipMemcpyDeviceToDevice, stream);
}

// Round 3
// 323.697 us; speedup vs baseline: 2.5159x; 1.7022x over previous
//
#include <hip/hip_runtime.h>

#define TTOK   8192
#define BGR    32
#define NNODE  256
#define DIM    128
#define NH     8
#define HD     16
#define NEDGE  262144
#define SCALE_QK 0.25f

// ---------------- GEMM ----------------
struct GemmJob {
  const float*  A1;
  const float*  A2;
  const float2* ss1;
  const float2* ss2;
  const float*  W;
  const float*  bias;
  const float*  res;
  float*        C;
};

// AMODE: 0 = A1 (lda=K); 1 = A1+A2 (both [M,128]); 2 = concat(bn(A1,ss1), bn(A2,ss2)) K=256
template<int AMODE, int RELU, int HASRES>
__global__ __launch_bounds__(256) void gemm_k(GemmJob j0, GemmJob j1, GemmJob j2,
                                              int M, int N, int K)
{
  const GemmJob jb = (blockIdx.z == 0) ? j0 : ((blockIdx.z == 1) ? j1 : j2);
  __shared__ float As[32][68];   // [k][m], transposed
  __shared__ float Ws[32][68];   // [k][n]
  const int bm = blockIdx.y * 64;
  const int bn = blockIdx.x * 64;
  const int tid = threadIdx.x;
  const int tx = tid & 15, ty = tid >> 4;
  const int r0 = ty * 4, c0 = tx * 4;
  float acc00=0,acc01=0,acc02=0,acc03=0;
  float acc10=0,acc11=0,acc12=0,acc13=0;
  float acc20=0,acc21=0,acc22=0,acc23=0;
  float acc30=0,acc31=0,acc32=0,acc33=0;

  for (int bk = 0; bk < K; bk += 32) {
    // A tile 64x32 -> As (transposed)
    {
      const int rbase = tid >> 3;
      const int kg = (tid & 7) * 4;
      #pragma unroll
      for (int half = 0; half < 2; half++) {
        const int rr = rbase + half * 32;
        const int row = bm + rr;
        const int k0 = bk + kg;
        float4 a;
        if (AMODE == 0) {
          a = *(const float4*)(jb.A1 + (size_t)row * K + k0);
        } else if (AMODE == 1) {
          float4 u = *(const float4*)(jb.A1 + (size_t)row * 128 + k0);
          float4 w = *(const float4*)(jb.A2 + (size_t)row * 128 + k0);
          a = make_float4(u.x + w.x, u.y + w.y, u.z + w.z, u.w + w.w);
        } else {
          if (k0 < 128) {
            float4 u = *(const float4*)(jb.A1 + (size_t)row * 128 + k0);
            float2 s0 = jb.ss1[k0], s1 = jb.ss1[k0+1], s2 = jb.ss1[k0+2], s3 = jb.ss1[k0+3];
            a = make_float4(u.x*s0.x+s0.y, u.y*s1.x+s1.y, u.z*s2.x+s2.y, u.w*s3.x+s3.y);
          } else {
            const int kq = k0 - 128;
            float4 u = *(const float4*)(jb.A2 + (size_t)row * 128 + kq);
            float2 s0 = jb.ss2[kq], s1 = jb.ss2[kq+1], s2 = jb.ss2[kq+2], s3 = jb.ss2[kq+3];
            a = make_float4(u.x*s0.x+s0.y, u.y*s1.x+s1.y, u.z*s2.x+s2.y, u.w*s3.x+s3.y);
          }
        }
        As[kg+0][rr] = a.x; As[kg+1][rr] = a.y; As[kg+2][rr] = a.z; As[kg+3][rr] = a.w;
      }
    }
    // W tile 32x64
    {
      const int kb = tid >> 4;
      const int cg = (tid & 15) * 4;
      #pragma unroll
      for (int half = 0; half < 2; half++) {
        const int kk2 = kb + half * 16;
        float4 w = *(const float4*)(jb.W + (size_t)(bk + kk2) * N + bn + cg);
        *(float4*)&Ws[kk2][cg] = w;
      }
    }
    __syncthreads();
    #pragma unroll
    for (int kk = 0; kk < 32; kk++) {
      const float4 av = *(const float4*)&As[kk][r0];
      const float4 bv = *(const float4*)&Ws[kk][c0];
      const float a0 = av.x, a1 = av.y, a2 = av.z, a3 = av.w;
      const float b0 = bv.x, b1 = bv.y, b2 = bv.z, b3 = bv.w;
      acc00 = fmaf(a0,b0,acc00); acc01 = fmaf(a0,b1,acc01); acc02 = fmaf(a0,b2,acc02); acc03 = fmaf(a0,b3,acc03);
      acc10 = fmaf(a1,b0,acc10); acc11 = fmaf(a1,b1,acc11); acc12 = fmaf(a1,b2,acc12); acc13 = fmaf(a1,b3,acc13);
      acc20 = fmaf(a2,b0,acc20); acc21 = fmaf(a2,b1,acc21); acc22 = fmaf(a2,b2,acc22); acc23 = fmaf(a2,b3,acc23);
      acc30 = fmaf(a3,b0,acc30); acc31 = fmaf(a3,b1,acc31); acc32 = fmaf(a3,b2,acc32); acc33 = fmaf(a3,b3,acc33);
    }
    __syncthreads();
  }

  const float bb0 = jb.bias[bn+c0+0], bb1 = jb.bias[bn+c0+1], bb2 = jb.bias[bn+c0+2], bb3 = jb.bias[bn+c0+3];
  #pragma unroll
  for (int i = 0; i < 4; i++) {
    const int row = bm + r0 + i;
    float o0, o1, o2, o3;
    if (i == 0) { o0=acc00; o1=acc01; o2=acc02; o3=acc03; }
    else if (i == 1) { o0=acc10; o1=acc11; o2=acc12; o3=acc13; }
    else if (i == 2) { o0=acc20; o1=acc21; o2=acc22; o3=acc23; }
    else { o0=acc30; o1=acc31; o2=acc32; o3=acc33; }
    o0 += bb0; o1 += bb1; o2 += bb2; o3 += bb3;
    if (RELU) { o0 = fmaxf(o0,0.f); o1 = fmaxf(o1,0.f); o2 = fmaxf(o2,0.f); o3 = fmaxf(o3,0.f); }
    if (HASRES) {
      float4 r = *(const float4*)(jb.res + (size_t)row * N + bn + c0);
      o0 += r.x; o1 += r.y; o2 += r.z; o3 += r.w;
    }
    *(float4*)(jb.C + (size_t)row * N + bn + c0) = make_float4(o0,o1,o2,o3);
  }
}

// ---------------- Fused attention v2: one thread per output row ----------------
// Block = one (b,h). 256 threads, thread t owns row t. K/V staged in LDS and
// read at uniform (broadcast) addresses. Two passes: A = exact max/min of
// scaled scores; B = exp/PV/entropy accumulation (no rescaling needed).
// Entropy analytically: -sum p ln p = m + ln Z - (sum e_j s_j)/Z.
__global__ __launch_bounds__(256) void attn2_k(
    const float* __restrict__ q, const float* __restrict__ k, const float* __restrict__ v,
    const float* __restrict__ tptr, float* __restrict__ fc, float* __restrict__ ff,
    float* __restrict__ dout)
{
  const int bh = blockIdx.x;
  const int b = bh >> 3, h = bh & 7;
  __shared__ float Ks[256][16];
  __shared__ float Vs[256][16];
  __shared__ float red[4][2];
  const int tid = threadIdx.x;
  // stage K/V rows (thread t loads row t)
  {
    const float* kr = k + ((size_t)(b*NNODE + tid))*DIM + h*HD;
    const float* vr = v + ((size_t)(b*NNODE + tid))*DIM + h*HD;
    #pragma unroll
    for (int p = 0; p < 4; p++) {
      *(float4*)&Ks[tid][4*p] = *(const float4*)(kr + 4*p);
      *(float4*)&Vs[tid][4*p] = *(const float4*)(vr + 4*p);
    }
  }
  // load q row, pre-scaled
  const float sc = SCALE_QK / tptr[0];
  float qa[16];
  {
    const float* qr = q + ((size_t)(b*NNODE + tid))*DIM + h*HD;
    #pragma unroll
    for (int p = 0; p < 4; p++) {
      float4 a = *(const float4*)(qr + 4*p);
      qa[4*p+0]=a.x*sc; qa[4*p+1]=a.y*sc; qa[4*p+2]=a.z*sc; qa[4*p+3]=a.w*sc;
    }
  }
  __syncthreads();

  // Pass A: exact max / min of s_j
  float mx = -1e30f, mn = 1e30f;
  #pragma unroll 2
  for (int j = 0; j < NNODE; j++) {
    const float4 k0 = *(const float4*)&Ks[j][0];
    const float4 k1 = *(const float4*)&Ks[j][4];
    const float4 k2 = *(const float4*)&Ks[j][8];
    const float4 k3 = *(const float4*)&Ks[j][12];
    float s = qa[0]*k0.x;
    float s1 = qa[1]*k0.y, s2 = qa[2]*k0.z, s3 = qa[3]*k0.w;
    s  = fmaf(qa[4],  k1.x, s);  s1 = fmaf(qa[5],  k1.y, s1);
    s2 = fmaf(qa[6],  k1.z, s2); s3 = fmaf(qa[7],  k1.w, s3);
    s  = fmaf(qa[8],  k2.x, s);  s1 = fmaf(qa[9],  k2.y, s1);
    s2 = fmaf(qa[10], k2.z, s2); s3 = fmaf(qa[11], k2.w, s3);
    s  = fmaf(qa[12], k3.x, s);  s1 = fmaf(qa[13], k3.y, s1);
    s2 = fmaf(qa[14], k3.z, s2); s3 = fmaf(qa[15], k3.w, s3);
    s = (s + s1) + (s2 + s3);
    mx = fmaxf(mx, s); mn = fminf(mn, s);
  }

  // Pass B: accumulate
  float zc = 0.f, zf = 0.f, Ec = 0.f, Ef = 0.f;
  float oc[16], of[16];
  #pragma unroll
  for (int d = 0; d < 16; d++) { oc[d] = 0.f; of[d] = 0.f; }
  #pragma unroll 2
  for (int j = 0; j < NNODE; j++) {
    const float4 k0 = *(const float4*)&Ks[j][0];
    const float4 k1 = *(const float4*)&Ks[j][4];
    const float4 k2 = *(const float4*)&Ks[j][8];
    const float4 k3 = *(const float4*)&Ks[j][12];
    float s = qa[0]*k0.x;
    float s1 = qa[1]*k0.y, s2 = qa[2]*k0.z, s3 = qa[3]*k0.w;
    s  = fmaf(qa[4],  k1.x, s);  s1 = fmaf(qa[5],  k1.y, s1);
    s2 = fmaf(qa[6],  k1.z, s2); s3 = fmaf(qa[7],  k1.w, s3);
    s  = fmaf(qa[8],  k2.x, s);  s1 = fmaf(qa[9],  k2.y, s1);
    s2 = fmaf(qa[10], k2.z, s2); s3 = fmaf(qa[11], k2.w, s3);
    s  = fmaf(qa[12], k3.x, s);  s1 = fmaf(qa[13], k3.y, s1);
    s2 = fmaf(qa[14], k3.z, s2); s3 = fmaf(qa[15], k3.w, s3);
    s = (s + s1) + (s2 + s3);
    const float ec = __expf(s - mx);
    const float ef = __expf(mn - s);
    zc += ec; zf += ef;
    Ec = fmaf(ec, s, Ec);
    Ef = fmaf(ef, -s, Ef);
    const float4 v0 = *(const float4*)&Vs[j][0];
    const float4 v1 = *(const float4*)&Vs[j][4];
    const float4 v2 = *(const float4*)&Vs[j][8];
    const float4 v3 = *(const float4*)&Vs[j][12];
    oc[0]  = fmaf(ec, v0.x, oc[0]);  of[0]  = fmaf(ef, v0.x, of[0]);
    oc[1]  = fmaf(ec, v0.y, oc[1]);  of[1]  = fmaf(ef, v0.y, of[1]);
    oc[2]  = fmaf(ec, v0.z, oc[2]);  of[2]  = fmaf(ef, v0.z, of[2]);
    oc[3]  = fmaf(ec, v0.w, oc[3]);  of[3]  = fmaf(ef, v0.w, of[3]);
    oc[4]  = fmaf(ec, v1.x, oc[4]);  of[4]  = fmaf(ef, v1.x, of[4]);
    oc[5]  = fmaf(ec, v1.y, oc[5]);  of[5]  = fmaf(ef, v1.y, of[5]);
    oc[6]  = fmaf(ec, v1.z, oc[6]);  of[6]  = fmaf(ef, v1.z, of[6]);
    oc[7]  = fmaf(ec, v1.w, oc[7]);  of[7]  = fmaf(ef, v1.w, of[7]);
    oc[8]  = fmaf(ec, v2.x, oc[8]);  of[8]  = fmaf(ef, v2.x, of[8]);
    oc[9]  = fmaf(ec, v2.y, oc[9]);  of[9]  = fmaf(ef, v2.y, of[9]);
    oc[10] = fmaf(ec, v2.z, oc[10]); of[10] = fmaf(ef, v2.z, of[10]);
    oc[11] = fmaf(ec, v2.w, oc[11]); of[11] = fmaf(ef, v2.w, of[11]);
    oc[12] = fmaf(ec, v3.x, oc[12]); of[12] = fmaf(ef, v3.x, of[12]);
    oc[13] = fmaf(ec, v3.y, oc[13]); of[13] = fmaf(ef, v3.y, of[13]);
    oc[14] = fmaf(ec, v3.z, oc[14]); of[14] = fmaf(ef, v3.z, of[14]);
    oc[15] = fmaf(ec, v3.w, oc[15]); of[15] = fmaf(ef, v3.w, of[15]);
  }
  const float rc = 1.f / zc, rf = 1.f / zf;
  float entc = mx + __logf(zc) - Ec * rc;
  float entf = -mn + __logf(zf) - Ef * rf;

  // write PV outputs (thread owns its row)
  {
    float* pc = fc + ((size_t)(b*NNODE + tid))*DIM + h*HD;
    float* pf = ff + ((size_t)(b*NNODE + tid))*DIM + h*HD;
    #pragma unroll
    for (int p = 0; p < 4; p++) {
      *(float4*)(pc + 4*p) = make_float4(oc[4*p]*rc, oc[4*p+1]*rc, oc[4*p+2]*rc, oc[4*p+3]*rc);
      *(float4*)(pf + 4*p) = make_float4(of[4*p]*rf, of[4*p+1]*rf, of[4*p+2]*rf, of[4*p+3]*rf);
    }
  }

  // block-reduce entropies
  #pragma unroll
  for (int off = 1; off < 64; off <<= 1) {
    entc += __shfl_xor(entc, off);
    entf += __shfl_xor(entf, off);
  }
  const int wv = tid >> 6;
  if ((tid & 63) == 0) { red[wv][0] = entc; red[wv][1] = entf; }
  __syncthreads();
  if (tid == 0) {
    const float tc = red[0][0]+red[1][0]+red[2][0]+red[3][0];
    const float tf = red[0][1]+red[1][1]+red[2][1]+red[3][1];
    dout[3145728 + bh] = tc * (1.0f/256.0f);
    dout[3145984 + bh] = tf * (1.0f/256.0f);
  }
}

// ---------------- Edge sigmoid mask (one thread per (edge, head)) + dst histogram ----------------
__global__ __launch_bounds__(256) void edge_k(
    const float* __restrict__ q, const float* __restrict__ k,
    const int* __restrict__ ei, float* __restrict__ maskout, float* __restrict__ emc,
    int* __restrict__ cnt)
{
  const int gt = blockIdx.x * 256 + threadIdx.x;   // 0 .. E*8-1
  const int e = gt >> 3, h = gt & 7;
  const int src = ei[e];
  const int dst = ei[NEDGE + e];
  const float* qr = q + (size_t)src * DIM + h*HD;
  const float* kr = k + (size_t)dst * DIM + h*HD;
  float s = 0.f;
  #pragma unroll
  for (int p = 0; p < 4; p++) {
    float4 a = *(const float4*)(qr + 4*p);
    float4 c = *(const float4*)(kr + 4*p);
    s += a.x*c.x + a.y*c.y + a.z*c.z + a.w*c.w;
  }
  s *= SCALE_QK;
  const float sig = 1.f / (1.f + __expf(-s));
  maskout[gt] = sig;
  float m = sig;
  m += __shfl_xor(m, 1); m += __shfl_xor(m, 2); m += __shfl_xor(m, 4);
  if ((threadIdx.x & 7) == 0) {
    emc[e] = m * 0.125f;
    atomicAdd(&cnt[dst], 1);
  }
}

// ---------------- CSR build: exclusive scan over 8192 dst counters ----------------
__global__ __launch_bounds__(256) void scan_k(const int* __restrict__ cnt,
                                              int* __restrict__ off,
                                              int* __restrict__ cursor)
{
  __shared__ int part[256];
  const int t = threadIdx.x;
  const int base = t * 32;
  int local[32];
  int s = 0;
  #pragma unroll
  for (int i = 0; i < 32; i++) { local[i] = s; s += cnt[base + i]; }
  part[t] = s;
  __syncthreads();
  int pre = 0;
  for (int i = 0; i < t; i++) pre += part[i];
  #pragma unroll
  for (int i = 0; i < 32; i++) {
    const int v = pre + local[i];
    off[base + i] = v;
    cursor[base + i] = v;
  }
  if (t == 255) off[8192] = pre + s;
}

__global__ __launch_bounds__(256) void place_k(const int* __restrict__ ei,
                                               int* __restrict__ cursor,
                                               int* __restrict__ elist)
{
  const int e = blockIdx.x * 256 + threadIdx.x;
  const int d = ei[NEDGE + e];
  const int pos = atomicAdd(&cursor[d], 1);
  elist[pos] = e;
}

// ---------------- GINE gather-aggregate (CSR, no atomics, no LDS) ----------------
__global__ __launch_bounds__(256) void gine_gather_k(
    const float* __restrict__ x, const float* __restrict__ ea,
    const int* __restrict__ ei, const float* __restrict__ emc,
    const int* __restrict__ off, const int* __restrict__ elist,
    float* __restrict__ aggrC, float* __restrict__ aggrF)
{
  const int warp = threadIdx.x >> 6, lane = threadIdx.x & 63;
  const int half = lane >> 5, c = lane & 31;
  const int n = blockIdx.x * 8 + warp * 2 + half;   // node 0..8191
  const int c4 = c * 4;
  float4 aC = make_float4(0,0,0,0), aF = make_float4(0,0,0,0);
  int i = off[n];
  const int end = off[n + 1];
  if (i < end) {
    int e = elist[i];
    int s = ei[e];
    float mc = emc[e];
    for (;;) {
      const float4 u = *(const float4*)(x  + (size_t)s * DIM + c4);
      const float4 w = *(const float4*)(ea + (size_t)e * DIM + c4);
      int en = 0, sn = 0; float mcn = 0.f;
      if (i + 1 < end) { en = elist[i + 1]; sn = ei[en]; mcn = emc[en]; }
      const float mf = 1.f - mc;
      const float m0 = fmaxf(u.x + w.x, 0.f);
      const float m1 = fmaxf(u.y + w.y, 0.f);
      const float m2 = fmaxf(u.z + w.z, 0.f);
      const float m3 = fmaxf(u.w + w.w, 0.f);
      aC.x = fmaf(m0, mc, aC.x); aC.y = fmaf(m1, mc, aC.y);
      aC.z = fmaf(m2, mc, aC.z); aC.w = fmaf(m3, mc, aC.w);
      aF.x = fmaf(m0, mf, aF.x); aF.y = fmaf(m1, mf, aF.y);
      aF.z = fmaf(m2, mf, aF.z); aF.w = fmaf(m3, mf, aF.w);
      i++;
      if (i >= end) break;
      e = en; s = sn; mc = mcn;
    }
  }
  *(float4*)(aggrC + (size_t)n * DIM + c4) = aC;
  *(float4*)(aggrF + (size_t)n * DIM + c4) = aF;
}

// ---------------- BatchNorm stats (2-stage, deterministic) ----------------
__global__ __launch_bounds__(128) void bn_part_k(
    const float* X0, const float* X1, const float* X2, const float* X3,
    float* __restrict__ psum, float* __restrict__ psq)
{
  const int ti = blockIdx.y, chunk = blockIdx.x, col = threadIdx.x;
  const float* X = (ti == 0) ? X0 : (ti == 1) ? X1 : (ti == 2) ? X2 : X3;
  const float* p = X + (size_t)chunk * 256 * DIM + col;
  float s = 0.f, sq = 0.f;
  for (int r = 0; r < 256; r++) {
    const float xv = p[(size_t)r * DIM];
    s += xv; sq += xv * xv;
  }
  psum[(ti*32 + chunk)*DIM + col] = s;
  psq [(ti*32 + chunk)*DIM + col] = sq;
}

__global__ __launch_bounds__(128) void bn_final_k(
    const float* __restrict__ psum, const float* __restrict__ psq,
    const float* g0, const float* g1, const float* g2, const float* g3,
    const float* b0, const float* b1, const float* b2, const float* b3,
    float2* __restrict__ ss)
{
  const int ti = blockIdx.x, col = threadIdx.x;
  const float* g = (ti == 0) ? g0 : (ti == 1) ? g1 : (ti == 2) ? g2 : g3;
  const float* bb = (ti == 0) ? b0 : (ti == 1) ? b1 : (ti == 2) ? b2 : b3;
  float s = 0.f, sq = 0.f;
  for (int c = 0; c < 32; c++) { s += psum[(ti*32 + c)*DIM + col]; sq += psq[(ti*32 + c)*DIM + col]; }
  const float mean = s * (1.f/8192.f);
  const float var  = sq * (1.f/8192.f) - mean*mean;
  const float istd = rsqrtf(var + 1e-5f);
  const float scale = g[col] * istd;
  ss[ti*DIM + col] = make_float2(scale, bb[col] - mean*scale);
}

// ---------------- Final outputs ----------------
__global__ __launch_bounds__(256) void final_k(
    const float* __restrict__ fmc, const float* __restrict__ fmf,
    const float2* __restrict__ ssc, const float2* __restrict__ ssf,
    float* __restrict__ dout)
{
  const int idx4 = blockIdx.x * 256 + threadIdx.x;   // 0..262143
  const int base = idx4 * 4;
  const int col = base & 127;
  const float4 a = *(const float4*)(fmc + base);
  const float4 b = *(const float4*)(fmf + base);
  const float2 s0 = ssc[col], s1 = ssc[col+1], s2 = ssc[col+2], s3 = ssc[col+3];
  const float2 t0 = ssf[col], t1 = ssf[col+1], t2 = ssf[col+2], t3 = ssf[col+3];
  const float c0 = a.x*s0.x + s0.y, c1 = a.y*s1.x + s1.y, c2 = a.z*s2.x + s2.y, c3 = a.w*s3.x + s3.y;
  const float f0 = b.x*t0.x + t0.y, f1 = b.y*t1.x + t1.y, f2 = b.z*t2.x + t2.y, f3 = b.w*t3.x + t3.y;
  *(float4*)(dout + 1048576 + base) = make_float4(c0,c1,c2,c3);
  *(float4*)(dout + 2097152 + base) = make_float4(f0,f1,f2,f3);
  *(float4*)(dout + base) = make_float4(0.5f*(c0+f0), 0.5f*(c1+f1), 0.5f*(c2+f2), 0.5f*(c3+f3));
}

// ---------------- Launcher ----------------
extern "C" void kernel_launch(void* const* d_in, const int* in_sizes, int n_in,
                              void* d_out, int out_size, void* d_ws, size_t ws_size,
                              hipStream_t stream)
{
  const float* x    = (const float*)d_in[0];
  const int*   ei   = (const int*)  d_in[2];
  const float* ea   = (const float*)d_in[3];
  const float* temp = (const float*)d_in[4];
  const float* cenc = (const float*)d_in[5];
  const float* fenc = (const float*)d_in[6];
  const float* Wq   = (const float*)d_in[7];
  const float* bq_v = (const float*)d_in[8];
  const float* Wk   = (const float*)d_in[9];
  const float* bk_v = (const float*)d_in[10];
  const float* Wv   = (const float*)d_in[11];
  const float* bv_v = (const float*)d_in[12];
  const float* Wo   = (const float*)d_in[13];
  const float* bo_v = (const float*)d_in[14];
  const float* Wg1  = (const float*)d_in[15];
  const float* bg1v = (const float*)d_in[16];
  const float* Wg2  = (const float*)d_in[17];
  const float* bg2v = (const float*)d_in[18];
  const float* Wam  = (const float*)d_in[19];
  const float* bamv = (const float*)d_in[20];
  const float* Wm1  = (const float*)d_in[21];
  const float* bm1v = (const float*)d_in[22];
  const float* Wm2  = (const float*)d_in[23];
  const float* bm2v = (const float*)d_in[24];
  const float* g_attn  = (const float*)d_in[25];
  const float* be_attn = (const float*)d_in[26];
  const float* g_mpnn  = (const float*)d_in[27];
  const float* be_mpnn = (const float*)d_in[28];
  const float* g_mlp   = (const float*)d_in[29];
  const float* be_mlp  = (const float*)d_in[30];

  float* out = (float*)d_out;
  float* ws  = (float*)d_ws;
  const size_t M1 = 1048576;

  float* q    = ws + 0*M1;
  float* kbuf = ws + 1*M1;
  float* vbuf = ws + 2*M1;
  float* fcp  = ws + 3*M1;
  float* ffp  = ws + 4*M1;
  float* acr  = ws + 5*M1;
  float* afr  = ws + 6*M1;
  float* agc  = ws + 7*M1;
  float* agf  = ws + 8*M1;
  float* ghc  = ws + 9*M1;    // 2M (also CSR ints before GINE1 gemm)
  float* ghf  = ws + 11*M1;   // 2M
  float* emc  = ws + 13*M1;   // 262144
  float* psum = ws + 13*M1 + 262144;   // 16384
  float* psq  = psum + 16384;          // 16384
  float2* ss  = (float2*)(psq + 16384);
  // CSR scratch lives in the ghc region (free until GINE layer-1 gemm)
  int* cnt    = (int*)(ws + 9*M1);     // 8192
  int* off_a  = cnt + 8192;            // 8193
  int* cursor = off_a + 8200;          // 8192
  int* elist  = cursor + 8192;         // 262144
  // reuses (sequenced by stream order)
  float* mcr = q;
  float* mfr = kbuf;
  float* fC  = vbuf;
  float* fF  = fcp;
  float* fhc = ghc;
  float* fhf = ghf;
  float* fmc = ffp;
  float* fmf = agc;

  hipMemsetAsync(cnt, 0, 8192*sizeof(int), stream);

  const dim3 blk(256);

  // QKV projections
  {
    GemmJob jq{x, nullptr, nullptr, nullptr, Wq, bq_v, nullptr, q};
    GemmJob jk{x, nullptr, nullptr, nullptr, Wk, bk_v, nullptr, kbuf};
    GemmJob jv{x, nullptr, nullptr, nullptr, Wv, bv_v, nullptr, vbuf};
    gemm_k<0,0,0><<<dim3(2,128,3), blk, 0, stream>>>(jq, jk, jv, TTOK, 128, 128);
  }
  // Fused attention + entropy
  attn2_k<<<dim3(256), blk, 0, stream>>>(q, kbuf, vbuf, temp, fcp, ffp, out);
  // Edge sigmoid masks + dst histogram
  edge_k<<<dim3(8192), blk, 0, stream>>>(q, kbuf, ei, out + 3408384, emc, cnt);
  // CSR build
  scan_k<<<dim3(1), blk, 0, stream>>>(cnt, off_a, cursor);
  place_k<<<dim3(1024), blk, 0, stream>>>(ei, cursor, elist);
  // GINE gather aggregation (no atomics)
  gine_gather_k<<<dim3(1024), blk, 0, stream>>>(x, ea, ei, emc, off_a, elist, agc, agf);
  // Wo projection
  {
    GemmJob j0{fcp, nullptr, nullptr, nullptr, Wo, bo_v, nullptr, acr};
    GemmJob j1{ffp, nullptr, nullptr, nullptr, Wo, bo_v, nullptr, afr};
    gemm_k<0,0,0><<<dim3(2,128,2), blk, 0, stream>>>(j0, j1, j0, TTOK, 128, 128);
  }
  // GINE layer 1 (h = x + aggr, relu)
  {
    GemmJob j0{x, agc, nullptr, nullptr, Wg1, bg1v, nullptr, ghc};
    GemmJob j1{x, agf, nullptr, nullptr, Wg1, bg1v, nullptr, ghf};
    gemm_k<1,1,0><<<dim3(4,128,2), blk, 0, stream>>>(j0, j1, j0, TTOK, 256, 128);
  }
  // GINE layer 2
  {
    GemmJob j0{ghc, nullptr, nullptr, nullptr, Wg2, bg2v, nullptr, mcr};
    GemmJob j1{ghf, nullptr, nullptr, nullptr, Wg2, bg2v, nullptr, mfr};
    gemm_k<0,0,0><<<dim3(2,128,2), blk, 0, stream>>>(j0, j1, j0, TTOK, 128, 256);
  }
  // BN stats round 1: acr, afr, mcr, mfr
  bn_part_k<<<dim3(32,4), dim3(128), 0, stream>>>(acr, afr, mcr, mfr, psum, psq);
  bn_final_k<<<dim3(4), dim3(128), 0, stream>>>(psum, psq,
      g_attn, g_attn, g_mpnn, g_mpnn, be_attn, be_attn, be_mpnn, be_mpnn, ss);
  // Fuse linear: concat(bn(attn), bn(mpnn)) @ Wam + bam
  {
    GemmJob j0{acr, mcr, ss + 0,   ss + 256, Wam, bamv, nullptr, fC};
    GemmJob j1{afr, mfr, ss + 128, ss + 384, Wam, bamv, nullptr, fF};
    gemm_k<2,0,0><<<dim3(2,128,2), blk, 0, stream>>>(j0, j1, j0, TTOK, 128, 256);
  }
  // Fuse MLP layer 1 (relu)
  {
    GemmJob j0{fC, nullptr, nullptr, nullptr, Wm1, bm1v, nullptr, fhc};
    GemmJob j1{fF, nullptr, nullptr, nullptr, Wm1, bm1v, nullptr, fhf};
    gemm_k<0,1,0><<<dim3(4,128,2), blk, 0, stream>>>(j0, j1, j0, TTOK, 256, 128);
  }
  // Fuse MLP layer 2 + residual f
  {
    GemmJob j0{fhc, nullptr, nullptr, nullptr, Wm2, bm2v, fC, fmc};
    GemmJob j1{fhf, nullptr, nullptr, nullptr, Wm2, bm2v, fF, fmf};
    gemm_k<0,0,1><<<dim3(2,128,2), blk, 0, stream>>>(j0, j1, j0, TTOK, 128, 256);
  }
  // BN stats round 2: fmc, fmf
  bn_part_k<<<dim3(32,2), dim3(128), 0, stream>>>(fmc, fmf, fmc, fmc, psum, psq);
  bn_final_k<<<dim3(2), dim3(128), 0, stream>>>(psum, psq,
      g_mlp, g_mlp, g_mlp, g_mlp, be_mlp, be_mlp, be_mlp, be_mlp, ss + 512);
  // Final features + new_x
  final_k<<<dim3(1024), blk, 0, stream>>>(fmc, fmf, ss + 512, ss + 640, out);
  // Pass-through encodings
  hipMemcpyAsync(out + 3146240, (const void*)cenc, 131072*sizeof(float),
                 hipMemcpyDeviceToDevice, stream);
  hipMemcpyAsync(out + 3277312, (const void*)fenc, 131072*sizeof(float),
                 hipMemcpyDeviceToDevice, stream);
}